// Round 6
// baseline (176.773 us; speedup 1.0000x reference)
//
#include <hip/hip_runtime.h>
#include <cmath>

// ---------------------------------------------------------------------------
// Problem constants (from reference)
// ---------------------------------------------------------------------------
constexpr int kNsh    = 9;      // (LMAX+1)^2, LMAX=2
constexpr int kF      = 64;
constexpr int kNrbf   = 20;
constexpr int kNAtoms = 1000;
constexpr int kNPairs = 10000;
constexpr float kCutoffF = 5.0f;
constexpr int kMaxNZ  = 200;
constexpr int kCp     = 12;         // channel dim padded (9 -> 12) for b128
constexpr int kXs     = kF * kCp;   // 768 floats per atom, internal layout
constexpr int kDx     = kNsh * kF;  // 576 floats per atom, dx scatter buffer

// ---------------------------------------------------------------------------
// Compile-time real Clebsch-Gordan table (mirrors the reference _real_cg)
// ---------------------------------------------------------------------------
struct CGSparse {
  int n;
  int c[kMaxNZ];
  int a[kMaxNZ];
  int b[kMaxNZ];
  float v[kMaxNZ];
};

constexpr double cfact(int n) {
  double r = 1.0;
  for (int i = 2; i <= n; i++) r *= (double)i;
  return r;
}
constexpr double cabs_(double x) { return x < 0 ? -x : x; }
constexpr double csqrt_(double x) {
  if (x <= 0.0) return 0.0;
  double g = x < 1.0 ? 1.0 : x;
  for (int i = 0; i < 60; i++) g = 0.5 * (g + x / g);
  return g;
}

constexpr double cg_cplx(int l1, int m1, int l2, int m2, int l3, int m3) {
  if (m3 != m1 + m2) return 0.0;
  int lo = l1 > l2 ? l1 - l2 : l2 - l1;
  if (l3 < lo || l3 > l1 + l2) return 0.0;
  double pre = csqrt_((2 * l3 + 1) * cfact(l3 + l1 - l2) * cfact(l3 - l1 + l2) *
                      cfact(l1 + l2 - l3) / cfact(l1 + l2 + l3 + 1));
  pre *= csqrt_(cfact(l3 + m3) * cfact(l3 - m3) * cfact(l1 - m1) *
                cfact(l1 + m1) * cfact(l2 - m2) * cfact(l2 + m2));
  double s = 0.0;
  for (int k = 0; k <= l1 + l2 - l3; k++) {
    int d0 = k, d1 = l1 + l2 - l3 - k, d2 = l1 - m1 - k;
    int d3 = l2 + m2 - k, d4 = l3 - l2 + m1 + k, d5 = l3 - l1 - m2 + k;
    if (d0 < 0 || d1 < 0 || d2 < 0 || d3 < 0 || d4 < 0 || d5 < 0) continue;
    double den = cfact(d0) * cfact(d1) * cfact(d2) * cfact(d3) * cfact(d4) * cfact(d5);
    s += ((k % 2) ? -1.0 : 1.0) / den;
  }
  return pre * s;
}

constexpr CGSparse build_cg() {
  CGSparse out{};
  int lidx[9] = {0, 1, 1, 1, 2, 2, 2, 2, 2};
  int midx[9] = {0, -1, 0, 1, -2, -1, 0, 1, 2};
  double Ur[9][9] = {};
  double Ui[9][9] = {};
  for (int l = 0; l <= 2; l++) {
    int base = l * l + l;
    Ur[base][base] = 1.0;
    for (int m = 1; m <= l; m++) {
      double s2 = 1.0 / csqrt_(2.0);
      double sgn = (m % 2) ? -1.0 : 1.0;
      Ur[base + m][base - m] = s2;
      Ur[base + m][base + m] = sgn * s2;
      Ui[base - m][base - m] = s2;
      Ui[base - m][base + m] = -sgn * s2;
    }
  }
  double cgr[9][9][9] = {};
  for (int i = 0; i < 9; i++)
    for (int j = 0; j < 9; j++)
      for (int k = 0; k < 9; k++) {
        double cv = cg_cplx(lidx[i], midx[i], lidx[j], midx[j], lidx[k], midx[k]);
        if (cv == 0.0) continue;
        for (int a2 = 0; a2 < 9; a2++) {
          if (Ur[a2][i] == 0.0 && Ui[a2][i] == 0.0) continue;
          for (int b2 = 0; b2 < 9; b2++) {
            if (Ur[b2][j] == 0.0 && Ui[b2][j] == 0.0) continue;
            for (int c2 = 0; c2 < 9; c2++) {
              if (Ur[c2][k] == 0.0 && Ui[c2][k] == 0.0) continue;
              double ar = Ur[a2][i], ai = Ui[a2][i];
              double br = Ur[b2][j], bi = Ui[b2][j];
              double cr = Ur[c2][k], ci = -Ui[c2][k];  // conj
              double pr = ar * br - ai * bi;
              double pi = ar * bi + ai * br;
              double rr = pr * cr - pi * ci;  // real part
              cgr[c2][a2][b2] += rr * cv;
            }
          }
        }
      }
  int n = 0;
  for (int c2 = 0; c2 < 9; c2++)
    for (int a2 = 0; a2 < 9; a2++)
      for (int b2 = 0; b2 < 9; b2++) {
        bool mask = ((lidx[a2] + lidx[b2]) % 2) == (lidx[c2] % 2);
        double v = mask ? cgr[c2][a2][b2] : 0.0;
        if (cabs_(v) > 1e-9) {
          out.c[n] = c2;
          out.a[n] = a2;
          out.b[n] = b2;
          out.v[n] = (float)v;
          n++;
        }
      }
  out.n = n;
  return out;
}

constexpr CGSparse CG = build_cg();
static_assert(CG.n > 0 && CG.n <= kMaxNZ, "CG table size out of range");

// ---------------------------------------------------------------------------
// k_msg<T>: PAIR-PARALLEL message. One wave per pair (2500 blocks x 4 waves
// = 10000 waves = 39 waves/CU -> latency fully hidden by TLP).
// Per pair: rebuild filter from Wf (L1-resident, 60 loads/lane) + redundant
// per-lane radial (20 expf, cheap), CG product, scatter 9 atomicAdd/lane
// into dxg[atom][c][f]. No seg, no LDS, no barriers.
// T==0: x_j = emb[Z[j]] channel 0 only (CG folds to a==0 entries).
// T==1: x_j = x_in (internal [f][12] layout).
// ---------------------------------------------------------------------------
template <int T>
__global__ __launch_bounds__(256) void k_msg(
    const float* __restrict__ rij, const int* __restrict__ idx_i,
    const int* __restrict__ idx_j, const int* __restrict__ Z,
    const float* __restrict__ emb, const float* __restrict__ Wft,
    const float* __restrict__ bft, const float* __restrict__ x_in,
    float* __restrict__ dxg) {
  const int p = blockIdx.x * 4 + (threadIdx.x >> 6);
  const int f = threadIdx.x & 63;

  // wave-uniform pair geometry (scalarizes: p is lane-independent)
  const float rx = rij[3 * p + 0], ry = rij[3 * p + 1], rz = rij[3 * p + 2];
  const float d = sqrtf(rx * rx + ry * ry + rz * rz);
  const float inv = 1.0f / d;
  const float ux = rx * inv, uy = ry * inv, uz = rz * inv;
  const float cut = (d < kCutoffF) ? 0.5f * (cosf(d * (float)(M_PI / 5.0)) + 1.0f) : 0.0f;

  // real spherical harmonics (uniform per wave)
  const float c0 = 0.28209479177387814f;  // 0.5/sqrt(pi)
  const float c1 = 0.4886025119029199f;   // sqrt(3/(4pi))
  const float c2 = 1.0925484305920792f;   // 0.5*sqrt(15/pi)
  const float c3 = 0.31539156525252005f;  // 0.25*sqrt(5/pi)
  const float c4 = 0.5462742152960396f;   // 0.25*sqrt(15/pi)
  float Y[9];
  Y[0] = c0;
  Y[1] = c1 * uy;
  Y[2] = c1 * uz;
  Y[3] = c1 * ux;
  Y[4] = c2 * ux * uy;
  Y[5] = c2 * uy * uz;
  Y[6] = c3 * (3.0f * uz * uz - 1.0f);
  Y[7] = c2 * ux * uz;
  Y[8] = c4 * (ux * ux - uy * uy);

  // radial basis * cut (uniform per wave; 20 expf, ~80 VALU)
  const float width = kCutoffF / (kNrbf - 1);
  const float coef = -0.5f / (width * width);
  float rad[kNrbf];
  #pragma unroll
  for (int k = 0; k < kNrbf; k++) {
    float off = (kCutoffF * k) / (kNrbf - 1);
    float tt = d - off;
    rad[k] = expf(coef * tt * tt) * cut;
  }

  // per-lane filters: Wl = bf*cut + sum_k rad_k * Wf[k]  (Wf L1-resident)
  float Wl0 = bft[f] * cut, Wl1 = bft[64 + f] * cut, Wl2 = bft[128 + f] * cut;
  #pragma unroll 5
  for (int k = 0; k < kNrbf; k++) {
    Wl0 += rad[k] * Wft[k * 192 + f];
    Wl1 += rad[k] * Wft[k * 192 + 64 + f];
    Wl2 += rad[k] * Wft[k * 192 + 128 + f];
  }

  float YW[9];
  YW[0] = Y[0] * Wl0;
  YW[1] = Y[1] * Wl1;
  YW[2] = Y[2] * Wl1;
  YW[3] = Y[3] * Wl1;
  #pragma unroll
  for (int b = 4; b < 9; b++) YW[b] = Y[b] * Wl2;

  const int i = idx_i[p];   // wave-uniform target atom
  const int j = idx_j[p];   // wave-uniform source atom

  float y[9];
  #pragma unroll
  for (int c = 0; c < 9; c++) y[c] = 0.f;
  if (T == 0) {
    float e = emb[Z[j] * kF + f];
    #pragma unroll
    for (int q = 0; q < CG.n; q++) {
      if (CG.a[q] == 0) y[CG.c[q]] += CG.v[q] * YW[CG.b[q]] * e;
    }
  } else {
    const float* xj = x_in + j * kXs + f * kCp;
    float xv[12];
    *(float4*)&xv[0] = *(const float4*)(xj + 0);
    *(float4*)&xv[4] = *(const float4*)(xj + 4);
    *(float4*)&xv[8] = *(const float4*)(xj + 8);
    #pragma unroll
    for (int q = 0; q < CG.n; q++) {
      y[CG.c[q]] += CG.v[q] * YW[CG.b[q]] * xv[CG.a[q]];
    }
  }

  float* dst = dxg + i * kDx + f;
  #pragma unroll
  for (int c = 0; c < 9; c++) {
    atomicAdd(dst + c * kF, y[c]);
  }
}

// ---------------------------------------------------------------------------
// mm_stream: acc[c] = sum_k dxLDS[c][k] * W[k][f]   (c = 0..8, k = 0..63)
// dxLDS reads are wave-uniform broadcast (conflict-free b128); W column reads
// are lane-coalesced (L1/L2-broadcast across the 1000 blocks).
// ---------------------------------------------------------------------------
__device__ __forceinline__ void mm_stream(const float* __restrict__ sDx,
                                          const float* __restrict__ W,
                                          int f, float* __restrict__ acc) {
  #pragma unroll
  for (int c = 0; c < 9; c++) acc[c] = 0.f;
  #pragma unroll 4
  for (int kq = 0; kq < 16; kq++) {
    float w0 = W[(4 * kq + 0) * kF + f];
    float w1 = W[(4 * kq + 1) * kF + f];
    float w2 = W[(4 * kq + 2) * kF + f];
    float w3 = W[(4 * kq + 3) * kF + f];
    #pragma unroll
    for (int c = 0; c < 9; c++) {
      float4 dv = *(const float4*)(sDx + c * kF + 4 * kq);
      acc[c] += dv.x * w0 + dv.y * w1 + dv.z * w2 + dv.w * w3;
    }
  }
}

// ---------------------------------------------------------------------------
// k_upd<T>: atom-parallel update, one wave per atom, barrier-free
// (single-wave blocks: __syncthreads compiles to a waitcnt, no convoy).
// Reads the scatter-accumulated dxg, runs mm1/tp/mm2/gate/mm3 + residual.
// T==0: residual emb (channel 0), write internal [f][12] to x_out.
// T==1: residual x_in (internal), write standard [c][f] to x_out.
// ---------------------------------------------------------------------------
template <int T>
__global__ __launch_bounds__(64) void k_upd(
    const int* __restrict__ Z, const float* __restrict__ emb,
    const float* __restrict__ W1, const float* __restrict__ W2,
    const float* __restrict__ W3, const float* __restrict__ Wg,
    const float* __restrict__ bg, const float* __restrict__ dxg,
    const float* __restrict__ x_in, float* __restrict__ x_out) {
  const int atom = blockIdx.x;
  const int f = threadIdx.x;

  __shared__ __align__(16) float dxLDS[kNsh * kF];   // 2.3 KB
  __shared__ __align__(16) float rowLDS[kF];         // 256 B

  // ---- load dx (coalesced per channel) ----
  float y[9];
  #pragma unroll
  for (int c = 0; c < 9; c++) y[c] = dxg[atom * kDx + c * kF + f];

  // mm1: ddx = dx @ W1
  #pragma unroll
  for (int c = 0; c < 9; c++) dxLDS[c * kF + f] = y[c];
  __syncthreads();
  float ddx[9];
  mm_stream(dxLDS, W1, f, ddx);

  // t2 = dx + CG(dx, ddx)   (purely lane-local)
  float t2[9];
  #pragma unroll
  for (int c = 0; c < 9; c++) t2[c] = y[c];
  #pragma unroll
  for (int q = 0; q < CG.n; q++) {
    t2[CG.c[q]] += CG.v[q] * y[CG.a[q]] * ddx[CG.b[q]];
  }

  // mm2: dx2 = t2 @ W2
  __syncthreads();  // WAR on dxLDS
  #pragma unroll
  for (int c = 0; c < 9; c++) dxLDS[c * kF + f] = t2[c];
  __syncthreads();
  float dx2[9];
  mm_stream(dxLDS, W2, f, dx2);

  // gate = sigmoid(dx2[0] @ Wg + bg)
  rowLDS[f] = dx2[0];
  __syncthreads();
  float g0 = bg[f], g1 = bg[64 + f], g2 = bg[128 + f];
  #pragma unroll 4
  for (int kq = 0; kq < 16; kq++) {
    float4 a4 = *(const float4*)(rowLDS + 4 * kq);
    float av[4] = {a4.x, a4.y, a4.z, a4.w};
    #pragma unroll
    for (int qq = 0; qq < 4; qq++) {
      const int k = 4 * kq + qq;
      g0 += av[qq] * Wg[k * 192 + f];
      g1 += av[qq] * Wg[k * 192 + 64 + f];
      g2 += av[qq] * Wg[k * 192 + 128 + f];
    }
  }
  g0 = 1.f / (1.f + expf(-g0));
  g1 = 1.f / (1.f + expf(-g1));
  g2 = 1.f / (1.f + expf(-g2));

  float dx3[9];
  dx3[0] = dx2[0] * g0;
  dx3[1] = dx2[1] * g1;
  dx3[2] = dx2[2] * g1;
  dx3[3] = dx2[3] * g1;
  #pragma unroll
  for (int c = 4; c < 9; c++) dx3[c] = dx2[c] * g2;

  // mm3: o = dx3 @ W3
  __syncthreads();  // WAR on dxLDS
  #pragma unroll
  for (int c = 0; c < 9; c++) dxLDS[c * kF + f] = dx3[c];
  __syncthreads();
  float o[9];
  mm_stream(dxLDS, W3, f, o);

  // ---- residual + store ----
  if (T == 0) {
    // residual = emb[Z[atom]] at channel 0; internal layout [f][12]
    float r0 = emb[Z[atom] * kF + f];
    float buf[12];
    #pragma unroll
    for (int c = 0; c < 9; c++) buf[c] = o[c];
    buf[0] += r0;
    buf[9] = 0.f; buf[10] = 0.f; buf[11] = 0.f;
    float* dst = x_out + atom * kXs + f * kCp;
    *(float4*)(dst + 0) = *(float4*)&buf[0];
    *(float4*)(dst + 4) = *(float4*)&buf[4];
    *(float4*)(dst + 8) = *(float4*)&buf[8];
  } else {
    // residual = x_in (internal); output standard [c][f]
    const float* xi = x_in + atom * kXs + f * kCp;
    float xv[12];
    *(float4*)&xv[0] = *(const float4*)(xi + 0);
    *(float4*)&xv[4] = *(const float4*)(xi + 4);
    *(float4*)&xv[8] = *(const float4*)(xi + 8);
    #pragma unroll
    for (int c = 0; c < 9; c++) {
      x_out[atom * (kNsh * kF) + c * kF + f] = o[c] + xv[c];
    }
  }
}

// ---------------------------------------------------------------------------
// Launch: memset(dxg) -> msg0 -> upd0 -> msg1 -> upd1
// (kernel boundaries provide all cross-phase coherence; atomics are
//  device-scope within each msg dispatch)
// ---------------------------------------------------------------------------
extern "C" void kernel_launch(void* const* d_in, const int* in_sizes, int n_in,
                              void* d_out, int out_size, void* d_ws, size_t ws_size,
                              hipStream_t stream) {
  const int* Z        = (const int*)d_in[0];
  const float* rij    = (const float*)d_in[1];
  const int* idx_i    = (const int*)d_in[2];
  const int* idx_j    = (const int*)d_in[3];
  const float* emb    = (const float*)d_in[4];
  const float* Wf     = (const float*)d_in[5];
  const float* bf     = (const float*)d_in[6];
  const float* W1     = (const float*)d_in[7];
  const float* W2     = (const float*)d_in[8];
  const float* W3     = (const float*)d_in[9];
  const float* Wg     = (const float*)d_in[10];
  const float* bg     = (const float*)d_in[11];
  float* out = (float*)d_out;

  float* x1   = (float*)d_ws;                  // 768,000 floats (internal)
  float* dxg0 = x1 + kNAtoms * kXs;            // 576,000 floats
  float* dxg1 = dxg0 + kNAtoms * kDx;          // 576,000 floats

  hipMemsetAsync(dxg0, 0, 2 * kNAtoms * kDx * sizeof(float), stream);

  // t = 0
  k_msg<0><<<kNPairs / 4, 256, 0, stream>>>(
      rij, idx_i, idx_j, Z, emb, Wf, bf, (const float*)nullptr, dxg0);
  k_upd<0><<<kNAtoms, 64, 0, stream>>>(
      Z, emb, W1, W2, W3, Wg, bg, dxg0, (const float*)nullptr, x1);

  // t = 1
  k_msg<1><<<kNPairs / 4, 256, 0, stream>>>(
      rij, idx_i, idx_j, Z, emb, Wf + kNrbf * 192, bf + 192, x1, dxg1);
  k_upd<1><<<kNAtoms, 64, 0, stream>>>(
      Z, emb, W1 + kF * kF, W2 + kF * kF, W3 + kF * kF,
      Wg + kF * 192, bg + 192, dxg1, x1, out);
}

// Round 7
// 166.753 us; speedup vs baseline: 1.0601x; 1.0601x over previous
//
#include <hip/hip_runtime.h>
#include <cmath>

// ---------------------------------------------------------------------------
// Problem constants (from reference)
// ---------------------------------------------------------------------------
constexpr int kNsh    = 9;      // (LMAX+1)^2, LMAX=2
constexpr int kF      = 64;
constexpr int kNrbf   = 20;
constexpr int kNAtoms = 1000;
constexpr int kNPairs = 10000;
constexpr float kCutoffF = 5.0f;
constexpr int kMaxNZ  = 200;
constexpr int kCp     = 12;         // channel dim padded (9 -> 12) for b128
constexpr int kXs     = kF * kCp;   // 768 floats per atom, internal layout
constexpr int kPY     = kF * kCp;   // 768 floats per pair, pairY [f][12]

// ---------------------------------------------------------------------------
// Compile-time real Clebsch-Gordan table (mirrors the reference _real_cg)
// ---------------------------------------------------------------------------
struct CGSparse {
  int n;
  int c[kMaxNZ];
  int a[kMaxNZ];
  int b[kMaxNZ];
  float v[kMaxNZ];
};

constexpr double cfact(int n) {
  double r = 1.0;
  for (int i = 2; i <= n; i++) r *= (double)i;
  return r;
}
constexpr double cabs_(double x) { return x < 0 ? -x : x; }
constexpr double csqrt_(double x) {
  if (x <= 0.0) return 0.0;
  double g = x < 1.0 ? 1.0 : x;
  for (int i = 0; i < 60; i++) g = 0.5 * (g + x / g);
  return g;
}

constexpr double cg_cplx(int l1, int m1, int l2, int m2, int l3, int m3) {
  if (m3 != m1 + m2) return 0.0;
  int lo = l1 > l2 ? l1 - l2 : l2 - l1;
  if (l3 < lo || l3 > l1 + l2) return 0.0;
  double pre = csqrt_((2 * l3 + 1) * cfact(l3 + l1 - l2) * cfact(l3 - l1 + l2) *
                      cfact(l1 + l2 - l3) / cfact(l1 + l2 + l3 + 1));
  pre *= csqrt_(cfact(l3 + m3) * cfact(l3 - m3) * cfact(l1 - m1) *
                cfact(l1 + m1) * cfact(l2 - m2) * cfact(l2 + m2));
  double s = 0.0;
  for (int k = 0; k <= l1 + l2 - l3; k++) {
    int d0 = k, d1 = l1 + l2 - l3 - k, d2 = l1 - m1 - k;
    int d3 = l2 + m2 - k, d4 = l3 - l2 + m1 + k, d5 = l3 - l1 - m2 + k;
    if (d0 < 0 || d1 < 0 || d2 < 0 || d3 < 0 || d4 < 0 || d5 < 0) continue;
    double den = cfact(d0) * cfact(d1) * cfact(d2) * cfact(d3) * cfact(d4) * cfact(d5);
    s += ((k % 2) ? -1.0 : 1.0) / den;
  }
  return pre * s;
}

constexpr CGSparse build_cg() {
  CGSparse out{};
  int lidx[9] = {0, 1, 1, 1, 2, 2, 2, 2, 2};
  int midx[9] = {0, -1, 0, 1, -2, -1, 0, 1, 2};
  double Ur[9][9] = {};
  double Ui[9][9] = {};
  for (int l = 0; l <= 2; l++) {
    int base = l * l + l;
    Ur[base][base] = 1.0;
    for (int m = 1; m <= l; m++) {
      double s2 = 1.0 / csqrt_(2.0);
      double sgn = (m % 2) ? -1.0 : 1.0;
      Ur[base + m][base - m] = s2;
      Ur[base + m][base + m] = sgn * s2;
      Ui[base - m][base - m] = s2;
      Ui[base - m][base + m] = -sgn * s2;
    }
  }
  double cgr[9][9][9] = {};
  for (int i = 0; i < 9; i++)
    for (int j = 0; j < 9; j++)
      for (int k = 0; k < 9; k++) {
        double cv = cg_cplx(lidx[i], midx[i], lidx[j], midx[j], lidx[k], midx[k]);
        if (cv == 0.0) continue;
        for (int a2 = 0; a2 < 9; a2++) {
          if (Ur[a2][i] == 0.0 && Ui[a2][i] == 0.0) continue;
          for (int b2 = 0; b2 < 9; b2++) {
            if (Ur[b2][j] == 0.0 && Ui[b2][j] == 0.0) continue;
            for (int c2 = 0; c2 < 9; c2++) {
              if (Ur[c2][k] == 0.0 && Ui[c2][k] == 0.0) continue;
              double ar = Ur[a2][i], ai = Ui[a2][i];
              double br = Ur[b2][j], bi = Ui[b2][j];
              double cr = Ur[c2][k], ci = -Ui[c2][k];  // conj
              double pr = ar * br - ai * bi;
              double pi = ar * bi + ai * br;
              double rr = pr * cr - pi * ci;  // real part
              cgr[c2][a2][b2] += rr * cv;
            }
          }
        }
      }
  int n = 0;
  for (int c2 = 0; c2 < 9; c2++)
    for (int a2 = 0; a2 < 9; a2++)
      for (int b2 = 0; b2 < 9; b2++) {
        bool mask = ((lidx[a2] + lidx[b2]) % 2) == (lidx[c2] % 2);
        double v = mask ? cgr[c2][a2][b2] : 0.0;
        if (cabs_(v) > 1e-9) {
          out.c[n] = c2;
          out.a[n] = a2;
          out.b[n] = b2;
          out.v[n] = (float)v;
          n++;
        }
      }
  out.n = n;
  return out;
}

constexpr CGSparse CG = build_cg();
static_assert(CG.n > 0 && CG.n <= kMaxNZ, "CG table size out of range");

// ---------------------------------------------------------------------------
// k_msg<T>: PAIR-PARALLEL message, NO ATOMICS. One wave per pair
// (2500 blocks x 4 waves = 10000 waves = 39 waves/CU).
// Per pair: rebuild filter from Wf (L1-resident), CG product, store the
// 9x64 message to pairY[p][f][12] (coalesced float4, fire-and-forget).
// idx_i is sorted -> pairs of one atom are contiguous -> k_upd reduces
// its slice [seg[a], seg[a+1]) with bulk streamed loads.
// T==0 additionally fills seg[] from idx_i boundaries (lane 0 per wave).
// ---------------------------------------------------------------------------
template <int T>
__global__ __launch_bounds__(256) void k_msg(
    const float* __restrict__ rij, const int* __restrict__ idx_i,
    const int* __restrict__ idx_j, const int* __restrict__ Z,
    const float* __restrict__ emb, const float* __restrict__ Wft,
    const float* __restrict__ bft, const float* __restrict__ x_in,
    float* __restrict__ pairY, int* __restrict__ seg) {
  const int p = blockIdx.x * 4 + (threadIdx.x >> 6);
  const int f = threadIdx.x & 63;

  // ---- seg fill (T==0 only): boundary writes from sorted idx_i ----
  if (T == 0) {
    if (f == 0) {
      const int hi = idx_i[p];
      const int lo = (p == 0) ? 0 : idx_i[p - 1] + 1;
      for (int a = lo; a <= hi; a++) seg[a] = p;   // seg[a]=first p with idx_i[p]>=a
    }
    if (f == 1 && p == kNPairs - 1) {
      const int hi = idx_i[p];
      for (int a = hi + 1; a <= kNAtoms; a++) seg[a] = kNPairs;
    }
  }

  // wave-uniform pair geometry (p is lane-independent)
  const float rx = rij[3 * p + 0], ry = rij[3 * p + 1], rz = rij[3 * p + 2];
  const float d = sqrtf(rx * rx + ry * ry + rz * rz);
  const float inv = 1.0f / d;
  const float ux = rx * inv, uy = ry * inv, uz = rz * inv;
  const float cut = (d < kCutoffF) ? 0.5f * (cosf(d * (float)(M_PI / 5.0)) + 1.0f) : 0.0f;

  // real spherical harmonics (uniform per wave)
  const float c0 = 0.28209479177387814f;  // 0.5/sqrt(pi)
  const float c1 = 0.4886025119029199f;   // sqrt(3/(4pi))
  const float c2 = 1.0925484305920792f;   // 0.5*sqrt(15/pi)
  const float c3 = 0.31539156525252005f;  // 0.25*sqrt(5/pi)
  const float c4 = 0.5462742152960396f;   // 0.25*sqrt(15/pi)
  float Y[9];
  Y[0] = c0;
  Y[1] = c1 * uy;
  Y[2] = c1 * uz;
  Y[3] = c1 * ux;
  Y[4] = c2 * ux * uy;
  Y[5] = c2 * uy * uz;
  Y[6] = c3 * (3.0f * uz * uz - 1.0f);
  Y[7] = c2 * ux * uz;
  Y[8] = c4 * (ux * ux - uy * uy);

  // radial basis * cut (uniform per wave)
  const float width = kCutoffF / (kNrbf - 1);
  const float coef = -0.5f / (width * width);
  float rad[kNrbf];
  #pragma unroll
  for (int k = 0; k < kNrbf; k++) {
    float off = (kCutoffF * k) / (kNrbf - 1);
    float tt = d - off;
    rad[k] = expf(coef * tt * tt) * cut;
  }

  // per-lane filters: Wl = bf*cut + sum_k rad_k * Wf[k]  (Wf L1-resident)
  float Wl0 = bft[f] * cut, Wl1 = bft[64 + f] * cut, Wl2 = bft[128 + f] * cut;
  #pragma unroll 5
  for (int k = 0; k < kNrbf; k++) {
    Wl0 += rad[k] * Wft[k * 192 + f];
    Wl1 += rad[k] * Wft[k * 192 + 64 + f];
    Wl2 += rad[k] * Wft[k * 192 + 128 + f];
  }

  float YW[9];
  YW[0] = Y[0] * Wl0;
  YW[1] = Y[1] * Wl1;
  YW[2] = Y[2] * Wl1;
  YW[3] = Y[3] * Wl1;
  #pragma unroll
  for (int b = 4; b < 9; b++) YW[b] = Y[b] * Wl2;

  const int j = idx_j[p];   // wave-uniform source atom

  float y[12];
  #pragma unroll
  for (int c = 0; c < 12; c++) y[c] = 0.f;
  if (T == 0) {
    float e = emb[Z[j] * kF + f];
    #pragma unroll
    for (int q = 0; q < CG.n; q++) {
      if (CG.a[q] == 0) y[CG.c[q]] += CG.v[q] * YW[CG.b[q]] * e;
    }
  } else {
    const float* xj = x_in + j * kXs + f * kCp;
    float xv[12];
    *(float4*)&xv[0] = *(const float4*)(xj + 0);
    *(float4*)&xv[4] = *(const float4*)(xj + 4);
    *(float4*)&xv[8] = *(const float4*)(xj + 8);
    #pragma unroll
    for (int q = 0; q < CG.n; q++) {
      y[CG.c[q]] += CG.v[q] * YW[CG.b[q]] * xv[CG.a[q]];
    }
  }

  // coalesced store: lane f writes 12 contiguous floats (3 x float4)
  float* dst = pairY + p * kPY + f * kCp;
  *(float4*)(dst + 0) = *(float4*)&y[0];
  *(float4*)(dst + 4) = *(float4*)&y[4];
  *(float4*)(dst + 8) = *(float4*)&y[8];
}

// ---------------------------------------------------------------------------
// mm_stream: acc[c] = sum_k dxLDS[c][k] * W[k][f]   (c = 0..8, k = 0..63)
// dxLDS reads are wave-uniform broadcast (conflict-free b128); W column reads
// are lane-coalesced (L1/L2-broadcast across the 1000 blocks).
// ---------------------------------------------------------------------------
__device__ __forceinline__ void mm_stream(const float* __restrict__ sDx,
                                          const float* __restrict__ W,
                                          int f, float* __restrict__ acc) {
  #pragma unroll
  for (int c = 0; c < 9; c++) acc[c] = 0.f;
  #pragma unroll 4
  for (int kq = 0; kq < 16; kq++) {
    float w0 = W[(4 * kq + 0) * kF + f];
    float w1 = W[(4 * kq + 1) * kF + f];
    float w2 = W[(4 * kq + 2) * kF + f];
    float w3 = W[(4 * kq + 3) * kF + f];
    #pragma unroll
    for (int c = 0; c < 9; c++) {
      float4 dv = *(const float4*)(sDx + c * kF + 4 * kq);
      acc[c] += dv.x * w0 + dv.y * w1 + dv.z * w2 + dv.w * w3;
    }
  }
}

// ---------------------------------------------------------------------------
// k_upd<T>: atom-parallel update, one wave per atom, barrier-free
// (single-wave blocks: __syncthreads compiles to a waitcnt, no convoy).
// Prologue: segmented reduction of pairY (contiguous rows, bulk float4
// streams, no dependent chain). Then mm1/tp/mm2/gate/mm3 + residual.
// T==0: residual emb (channel 0), write internal [f][12] to x_out.
// T==1: residual x_in (internal), write standard [c][f] to x_out.
// ---------------------------------------------------------------------------
template <int T>
__global__ __launch_bounds__(64) void k_upd(
    const int* __restrict__ Z, const float* __restrict__ emb,
    const float* __restrict__ W1, const float* __restrict__ W2,
    const float* __restrict__ W3, const float* __restrict__ Wg,
    const float* __restrict__ bg, const float* __restrict__ pairY,
    const int* __restrict__ seg, const float* __restrict__ x_in,
    float* __restrict__ x_out) {
  const int atom = blockIdx.x;
  const int f = threadIdx.x;

  __shared__ __align__(16) float dxLDS[kNsh * kF];   // 2.3 KB
  __shared__ __align__(16) float rowLDS[kF];         // 256 B

  // ---- segmented reduction: y[c] = sum_{p in segment} pairY[p][f][c] ----
  const int s0 = seg[atom], s1 = seg[atom + 1];
  float y[9];
  #pragma unroll
  for (int c = 0; c < 9; c++) y[c] = 0.f;
  for (int p = s0; p < s1; p++) {
    const float* py = pairY + p * kPY + f * kCp;
    float4 a = *(const float4*)(py + 0);
    float4 b = *(const float4*)(py + 4);
    float4 c4 = *(const float4*)(py + 8);
    y[0] += a.x; y[1] += a.y; y[2] += a.z; y[3] += a.w;
    y[4] += b.x; y[5] += b.y; y[6] += b.z; y[7] += b.w;
    y[8] += c4.x;
  }

  // mm1: ddx = dx @ W1
  #pragma unroll
  for (int c = 0; c < 9; c++) dxLDS[c * kF + f] = y[c];
  __syncthreads();
  float ddx[9];
  mm_stream(dxLDS, W1, f, ddx);

  // t2 = dx + CG(dx, ddx)   (purely lane-local)
  float t2[9];
  #pragma unroll
  for (int c = 0; c < 9; c++) t2[c] = y[c];
  #pragma unroll
  for (int q = 0; q < CG.n; q++) {
    t2[CG.c[q]] += CG.v[q] * y[CG.a[q]] * ddx[CG.b[q]];
  }

  // mm2: dx2 = t2 @ W2
  __syncthreads();  // WAR on dxLDS
  #pragma unroll
  for (int c = 0; c < 9; c++) dxLDS[c * kF + f] = t2[c];
  __syncthreads();
  float dx2[9];
  mm_stream(dxLDS, W2, f, dx2);

  // gate = sigmoid(dx2[0] @ Wg + bg)
  rowLDS[f] = dx2[0];
  __syncthreads();
  float g0 = bg[f], g1 = bg[64 + f], g2 = bg[128 + f];
  #pragma unroll 4
  for (int kq = 0; kq < 16; kq++) {
    float4 a4 = *(const float4*)(rowLDS + 4 * kq);
    float av[4] = {a4.x, a4.y, a4.z, a4.w};
    #pragma unroll
    for (int qq = 0; qq < 4; qq++) {
      const int k = 4 * kq + qq;
      g0 += av[qq] * Wg[k * 192 + f];
      g1 += av[qq] * Wg[k * 192 + 64 + f];
      g2 += av[qq] * Wg[k * 192 + 128 + f];
    }
  }
  g0 = 1.f / (1.f + expf(-g0));
  g1 = 1.f / (1.f + expf(-g1));
  g2 = 1.f / (1.f + expf(-g2));

  float dx3[9];
  dx3[0] = dx2[0] * g0;
  dx3[1] = dx2[1] * g1;
  dx3[2] = dx2[2] * g1;
  dx3[3] = dx2[3] * g1;
  #pragma unroll
  for (int c = 4; c < 9; c++) dx3[c] = dx2[c] * g2;

  // mm3: o = dx3 @ W3
  __syncthreads();  // WAR on dxLDS
  #pragma unroll
  for (int c = 0; c < 9; c++) dxLDS[c * kF + f] = dx3[c];
  __syncthreads();
  float o[9];
  mm_stream(dxLDS, W3, f, o);

  // ---- residual + store ----
  if (T == 0) {
    // residual = emb[Z[atom]] at channel 0; internal layout [f][12]
    float r0 = emb[Z[atom] * kF + f];
    float buf[12];
    #pragma unroll
    for (int c = 0; c < 9; c++) buf[c] = o[c];
    buf[0] += r0;
    buf[9] = 0.f; buf[10] = 0.f; buf[11] = 0.f;
    float* dst = x_out + atom * kXs + f * kCp;
    *(float4*)(dst + 0) = *(float4*)&buf[0];
    *(float4*)(dst + 4) = *(float4*)&buf[4];
    *(float4*)(dst + 8) = *(float4*)&buf[8];
  } else {
    // residual = x_in (internal); output standard [c][f]
    const float* xi = x_in + atom * kXs + f * kCp;
    float xv[12];
    *(float4*)&xv[0] = *(const float4*)(xi + 0);
    *(float4*)&xv[4] = *(const float4*)(xi + 4);
    *(float4*)&xv[8] = *(const float4*)(xi + 8);
    #pragma unroll
    for (int c = 0; c < 9; c++) {
      x_out[atom * (kNsh * kF) + c * kF + f] = o[c] + xv[c];
    }
  }
}

// ---------------------------------------------------------------------------
// Launch: msg0 -> upd0 -> msg1 -> upd1 (kernel boundaries = coherence;
// no atomics, no memset; seg produced inside msg0)
// ---------------------------------------------------------------------------
extern "C" void kernel_launch(void* const* d_in, const int* in_sizes, int n_in,
                              void* d_out, int out_size, void* d_ws, size_t ws_size,
                              hipStream_t stream) {
  const int* Z        = (const int*)d_in[0];
  const float* rij    = (const float*)d_in[1];
  const int* idx_i    = (const int*)d_in[2];
  const int* idx_j    = (const int*)d_in[3];
  const float* emb    = (const float*)d_in[4];
  const float* Wf     = (const float*)d_in[5];
  const float* bf     = (const float*)d_in[6];
  const float* W1     = (const float*)d_in[7];
  const float* W2     = (const float*)d_in[8];
  const float* W3     = (const float*)d_in[9];
  const float* Wg     = (const float*)d_in[10];
  const float* bg     = (const float*)d_in[11];
  float* out = (float*)d_out;

  float* x1    = (float*)d_ws;                    // 768,000 floats (internal)
  float* pairY = x1 + kNAtoms * kXs;              // 7,680,000 floats (30.7 MB)
  int*   seg   = (int*)(pairY + kNPairs * kPY);   // 1001 ints

  // t = 0
  k_msg<0><<<kNPairs / 4, 256, 0, stream>>>(
      rij, idx_i, idx_j, Z, emb, Wf, bf, (const float*)nullptr, pairY, seg);
  k_upd<0><<<kNAtoms, 64, 0, stream>>>(
      Z, emb, W1, W2, W3, Wg, bg, pairY, seg, (const float*)nullptr, x1);

  // t = 1
  k_msg<1><<<kNPairs / 4, 256, 0, stream>>>(
      rij, idx_i, idx_j, Z, emb, Wf + kNrbf * 192, bf + 192, x1, pairY, seg);
  k_upd<1><<<kNAtoms, 64, 0, stream>>>(
      Z, emb, W1 + kF * kF, W2 + kF * kF, W3 + kF * kF,
      Wg + kF * 192, bg + 192, pairY, seg, x1, out);
}